// Round 7
// baseline (52.939 us; speedup 1.0000x reference)
//
#include <hip/hip_runtime.h>

#define NEGV (-10000000000.0f)

typedef unsigned short u16;
typedef _Float16 __attribute__((ext_vector_type(8))) f16x8;
typedef __attribute__((ext_vector_type(4))) float f32x4;

__device__ __forceinline__ u16 f2fh(float f) {
  _Float16 h = (_Float16)f;
  return __builtin_bit_cast(u16, h);
}

__device__ __forceinline__ void gload16(const u16* g, u16* l) {
  __builtin_amdgcn_global_load_lds(
      (const __attribute__((address_space(1))) void*)g,
      (__attribute__((address_space(3))) void*)l, 16, 0, 0);
}

// ---------------------------------------------------------------------------
// prep: blocks 0..63  : fp16 convert query + W
//       blocks 64..575: fp16 convert one 64x64 kv tile -> kvh [k][d]
//                       AND kvhT [d][k] (LDS transpose)
// ---------------------------------------------------------------------------
__global__ __launch_bounds__(256) void prep(
    const float* __restrict__ query, const float* __restrict__ W,
    const float* __restrict__ kv,
    u16* __restrict__ qh, u16* __restrict__ wh,
    u16* __restrict__ kvh, u16* __restrict__ kvhT)
{
  const int id = blockIdx.x, t = threadIdx.x;
  if (id < 64) {
    int idx = id * 256 + t;      // float4 index over query(131072) ++ W(65536)
#pragma unroll
    for (int it = 0; it < 12; it++, idx += 16384) {
      const float4* src; u16* dst; int j;
      if (idx < 131072) { src = (const float4*)query; j = idx;          dst = qh; }
      else              { src = (const float4*)W;     j = idx - 131072; dst = wh; }
      float4 x = src[j];
      ushort4 o;
      o.x = f2fh(x.x); o.y = f2fh(x.y); o.z = f2fh(x.z); o.w = f2fh(x.w);
      *(ushort4*)&dst[(size_t)j * 4] = o;
    }
    return;
  }

  __shared__ float sT[64][68];       // [d_local][k_local], padded
  const int tile = id - 64;          // 0..511
  const int b  = tile >> 6;
  const int kt = (tile >> 3) & 7;
  const int dt = tile & 7;
  const int r  = t >> 2;             // 0..63
  const int c4 = t & 3;

  const float4* src = (const float4*)(kv + ((size_t)b * 512 + kt * 64) * 512 + dt * 64);
  ushort4* dkvh = (ushort4*)(kvh + ((size_t)b * 512 + kt * 64) * 512 + dt * 64);

#pragma unroll
  for (int i = 0; i < 4; i++) {
    int j = c4 * 4 + i;              // f4 col within tile, 0..15
    float4 x = src[(size_t)r * 128 + j];
    ushort4 o;
    o.x = f2fh(x.x); o.y = f2fh(x.y); o.z = f2fh(x.z); o.w = f2fh(x.w);
    dkvh[(size_t)r * 128 + j] = o;
    sT[j * 4 + 0][r] = x.x; sT[j * 4 + 1][r] = x.y;
    sT[j * 4 + 2][r] = x.z; sT[j * 4 + 3][r] = x.w;
  }
  __syncthreads();

  u16* dT = kvhT + ((size_t)b * 512 + dt * 64) * 512 + (size_t)kt * 64;
#pragma unroll
  for (int i = 0; i < 4; i++) {
    int j = c4 * 4 + i;
    float4 x = *(const float4*)&sT[r][j * 4];   // d_local = r, k_local = j*4..
    ushort4 o;
    o.x = f2fh(x.x); o.y = f2fh(x.y); o.z = f2fh(x.z); o.w = f2fh(x.w);
    *(ushort4*)&dT[(size_t)r * 512 + j * 4] = o;
  }
}

// ---------------------------------------------------------------------------
// 64x64 fp16 MFMA NT tile, 2-phase pipelined (double-buffered LDS; next-tile
// global_load_lds issued BEFORE current-tile compute; one barrier per K-step).
// EXPOUT: C = exp(2*(acc+bias))  else  C = acc + bias.
// XOR swizzle on global source + LDS read (both-sides rule).
// ---------------------------------------------------------------------------
template <bool EXPOUT>
__device__ __forceinline__ void gemm_mfma64(
    const u16* __restrict__ A, int lda,
    const u16* __restrict__ B, int ldb,
    float* __restrict__ C, int ldc,
    const float* __restrict__ bias,
    int bm, int bn, int t, u16* sA, u16* sB)   // sA,sB: 2*8*512 u16 each
{
  const int l = t & 63, w = t >> 6;
  const int wr = w >> 1, wc = w & 1;
  f32x4 acc[2][2] = {};

  const int srow = l >> 3;
  const int scol = ((l & 7) ^ srow) << 3;

  auto STAGE = [&](int buf, int k0) {
    u16* dA = sA + buf * 4096;
    u16* dB = sB + buf * 4096;
#pragma unroll
    for (int i = 0; i < 4; i++) {
      int s = w * 4 + i;                      // wave-uniform
      if (s < 8) {
        gload16(A + (size_t)(bm + s * 8 + srow) * lda + k0 + scol, dA + s * 512);
      } else {
        int s2 = s - 8;
        gload16(B + (size_t)(bn + s2 * 8 + srow) * ldb + k0 + scol, dB + s2 * 512);
      }
    }
  };

  STAGE(0, 0);
  __syncthreads();

  int cur = 0;
  for (int k0 = 0; k0 < 512; k0 += 64) {
    if (k0 + 64 < 512) STAGE(cur ^ 1, k0 + 64);   // overlap with compute below
    const u16* rA = sA + cur * 4096;
    const u16* rB = sB + cur * 4096;
#pragma unroll
    for (int ks = 0; ks < 2; ks++) {
      f16x8 af[2], bfr[2];
#pragma unroll
      for (int f = 0; f < 2; f++) {
        int row = wr * 32 + f * 16 + (l & 15);
        int cbA = ((ks * 32 + ((l >> 4) << 3)) << 1) ^ ((row & 7) << 4);
        af[f] = *(const f16x8*)((const char*)rA + row * 128 + cbA);
        int col = wc * 32 + f * 16 + (l & 15);
        int cbB = ((ks * 32 + ((l >> 4) << 3)) << 1) ^ ((col & 7) << 4);
        bfr[f] = *(const f16x8*)((const char*)rB + col * 128 + cbB);
      }
#pragma unroll
      for (int fm = 0; fm < 2; fm++)
#pragma unroll
        for (int fn = 0; fn < 2; fn++)
          acc[fm][fn] = __builtin_amdgcn_mfma_f32_16x16x32_f16(
              af[fm], bfr[fn], acc[fm][fn], 0, 0, 0);
    }
    __syncthreads();   // drains this iter's prefetch + guards buffer reuse
    cur ^= 1;
  }

#pragma unroll
  for (int fm = 0; fm < 2; fm++)
#pragma unroll
    for (int fn = 0; fn < 2; fn++) {
      int cn = bn + wc * 32 + fn * 16 + (l & 15);
      float bv = bias ? bias[cn] : 0.0f;
#pragma unroll
      for (int j = 0; j < 4; j++) {
        int rm = bm + wr * 32 + fm * 16 + (l >> 4) * 4 + j;
        float val = acc[fm][fn][j] + bv;
        C[(size_t)rm * ldc + cn] = EXPOUT ? __expf(val * 2.0f) : val;
      }
    }
}

// blocks 0..63: qpE (1024x256). blocks 64..319: kpE (8 b, 256a x 512k).
__global__ __launch_bounds__(256) void proj_mfma(
    const u16* __restrict__ qh, const u16* __restrict__ wh,
    const u16* __restrict__ kvh, const float* __restrict__ bias,
    float* __restrict__ qpE, float* __restrict__ kpE)
{
  __shared__ __align__(16) u16 sA[2 * 8 * 512];
  __shared__ __align__(16) u16 sB[2 * 8 * 512];
  const int id = blockIdx.x, t = threadIdx.x;
  if (id < 64) {
    gemm_mfma64<true>(qh, 512, wh, 1024, qpE, 256, bias,
                      (id >> 2) * 64, (id & 3) * 64, t, sA, sB);
  } else {
    int r = id - 64;
    int b = r >> 5, w5 = r & 31;
    gemm_mfma64<true>(wh + 512, 1024, kvh + (size_t)b * 512 * 512, 512,
                      kpE + (size_t)b * 256 * 512, 512, nullptr,
                      (w5 & 3) * 64, (w5 >> 2) * 64, t, sA, sB);
  }
}

// ---------------------------------------------------------------------------
// fused score + softmax. Block = 4 q rows x full 512 k (4 waves).
// Wave w, lane l owns k1 = w*64+l and k2 = k1+256.
// score'[q,k] = -sum_a 2 v_a / (1 + eq[q][a]*ek[a][k])  (softmax-equivalent)
// P fp16: masked q -> uniform 1/512; k>=klen -> 0.
// ---------------------------------------------------------------------------
__global__ __launch_bounds__(256) void score_softmax(
    const float* __restrict__ qpE,    // [B*128][256] = exp(2(qp+b))
    const float* __restrict__ kpE,    // [B][256][512] = exp(2kp)
    const float* __restrict__ v,      // [256]
    const int* __restrict__ qlen_p, const int* __restrict__ klen_p,
    u16* __restrict__ P)              // [B][128][512] fp16
{
  const int b = blockIdx.y, q0 = blockIdx.x * 4, t = threadIdx.x;
  const int w = t >> 6, l = t & 63;
  const int qlen = qlen_p[b], klen = klen_p[b];
  const int k1 = w * 64 + l, k2 = k1 + 256;
  u16* Pb = P + (size_t)(b * 128 + q0) * 512;

  if (q0 >= qlen) {                   // 4 fully-masked rows -> uniform 1/512
    const u16 uh = f2fh(1.0f / 512.0f);
#pragma unroll
    for (int j = 0; j < 4; j++) {
      Pb[(size_t)j * 512 + k1] = uh;
      Pb[(size_t)j * 512 + k2] = uh;
    }
    return;
  }

  __shared__ float sEq[4][256];
  __shared__ float sV2[256];
  __shared__ float sRed[4][8];        // [wave][q(max) ++ q(sum)]

  sV2[t] = 2.0f * v[t];
#pragma unroll
  for (int r = 0; r < 4; r++)
    sEq[r][t] = qpE[(size_t)(b * 128 + q0 + r) * 256 + t];
  __syncthreads();

  const float* kc = kpE + (size_t)b * 256 * 512;
  const bool c2 = (w * 64 + 256) < klen;

  float s1[4] = {0.f, 0.f, 0.f, 0.f};
  float s2[4] = {0.f, 0.f, 0.f, 0.f};
  if (c2) {
#pragma unroll 8
    for (int a = 0; a < 256; a++) {
      float ek1 = kc[(size_t)a * 512 + k1];
      float ek2 = kc[(size_t)a * 512 + k2];
      float vv = sV2[a];
#pragma unroll
      for (int j = 0; j < 4; j++) {
        float eq = sEq[j][a];
        s1[j] = fmaf(-vv, __builtin_amdgcn_rcpf(fmaf(eq, ek1, 1.0f)), s1[j]);
        s2[j] = fmaf(-vv, __builtin_amdgcn_rcpf(fmaf(eq, ek2, 1.0f)), s2[j]);
      }
    }
  } else {
#pragma unroll 8
    for (int a = 0; a < 256; a++) {
      float ek1 = kc[(size_t)a * 512 + k1];
      float vv = sV2[a];
#pragma unroll
      for (int j = 0; j < 4; j++) {
        float eq = sEq[j][a];
        s1[j] = fmaf(-vv, __builtin_amdgcn_rcpf(fmaf(eq, ek1, 1.0f)), s1[j]);
      }
    }
  }

#pragma unroll
  for (int j = 0; j < 4; j++) {
    if (k1 >= klen) s1[j] = NEGV;
    if (k2 >= klen) s2[j] = NEGV;
  }

  // per-row max (wave shuffle + LDS combine over 4 waves)
#pragma unroll
  for (int j = 0; j < 4; j++) {
    float x = fmaxf(s1[j], s2[j]);
#pragma unroll
    for (int off = 32; off > 0; off >>= 1) x = fmaxf(x, __shfl_xor(x, off));
    if (l == 0) sRed[w][j] = x;
  }
  __syncthreads();
  float M[4];
#pragma unroll
  for (int j = 0; j < 4; j++)
    M[j] = fmaxf(fmaxf(sRed[0][j], sRed[1][j]), fmaxf(sRed[2][j], sRed[3][j]));

  float e1[4], e2[4];
#pragma unroll
  for (int j = 0; j < 4; j++) {
    e1[j] = __expf(s1[j] - M[j]);
    e2[j] = __expf(s2[j] - M[j]);
    float su = e1[j] + e2[j];
#pragma unroll
    for (int off = 32; off > 0; off >>= 1) su += __shfl_xor(su, off);
    if (l == 0) sRed[w][4 + j] = su;
  }
  __syncthreads();

#pragma unroll
  for (int j = 0; j < 4; j++) {
    float S = (sRed[0][4 + j] + sRed[1][4 + j]) +
              (sRed[2][4 + j] + sRed[3][4 + j]);
    float rinv = __fdividef(1.0f, S);
    float p1 = e1[j] * rinv, p2 = e2[j] * rinv;
    if (q0 + j >= qlen) { p1 = 1.0f / 512.0f; p2 = 1.0f / 512.0f; }
    Pb[(size_t)j * 512 + k1] = f2fh(p1);
    Pb[(size_t)j * 512 + k2] = f2fh(p2);
  }
}

// pv: out[b] = P[b] @ kv[b]  (M=128 q, N=512 d, K=512 k), NT via kvhT.
__global__ __launch_bounds__(256) void pv_mfma(
    const u16* __restrict__ P, const u16* __restrict__ kvhT,
    float* __restrict__ out)
{
  __shared__ __align__(16) u16 sA[2 * 8 * 512];
  __shared__ __align__(16) u16 sB[2 * 8 * 512];
  const int id = blockIdx.x, t = threadIdx.x;
  const int b = id >> 4, r = id & 15;
  const int mt = r >> 3, nt = r & 7;
  gemm_mfma64<false>(P + (size_t)b * 128 * 512, 512,
                     kvhT + (size_t)b * 512 * 512, 512,
                     out + (size_t)b * 128 * 512, 512, nullptr,
                     mt * 64, nt * 64, t, sA, sB);
}

// ---------------------------------------------------------------------------
extern "C" void kernel_launch(void* const* d_in, const int* in_sizes, int n_in,
                              void* d_out, int out_size, void* d_ws, size_t ws_size,
                              hipStream_t stream)
{
  const float* query = (const float*)d_in[0];  // [8][128][512]
  const float* kv    = (const float*)d_in[1];  // [8][512][512]
  const float* W     = (const float*)d_in[2];  // [256][1024]
  const float* bbias = (const float*)d_in[3];  // [256]
  const float* v     = (const float*)d_in[4];  // [256]
  const int*   qlen  = (const int*)d_in[5];    // [8]
  const int*   klen  = (const int*)d_in[6];    // [8]
  float* out = (float*)d_out;                  // [8][128][512]

  // workspace layout with lifetime-based aliasing (total 14.5 MB):
  float* qpE  = (float*)d_ws;                  // 1MB   live: proj -> score
  float* kpE  = qpE + 1024 * 256;              // 4MB   live: proj -> score
  u16*   kvh  = (u16*)(kpE + 8 * 256 * 512);   // 4MB   live: prep -> proj
  u16*   kvhT = kvh + 8 * 512 * 512;           // 4MB   live: prep -> pv
  u16*   qh   = kvhT + 8 * 512 * 512;          // 1MB   live: prep -> proj
  u16*   P    = qh;                            // alias (1MB) live: score -> pv
  u16*   wh   = qh + 1024 * 512;               // 0.5MB live: prep -> proj

  prep<<<dim3(576), 256, 0, stream>>>(query, W, kv, qh, wh, kvh, kvhT);

  proj_mfma<<<dim3(320), 256, 0, stream>>>(qh, wh, kvh, bbias, qpE, kpE);

  score_softmax<<<dim3(32, 8), 256, 0, stream>>>(
      qpE, kpE, v, qlen, klen, P);

  pv_mfma<<<dim3(128), 256, 0, stream>>>(P, kvhT, out);
}